// Round 1
// baseline (215.022 us; speedup 1.0000x reference)
//
#include <hip/hip_runtime.h>

typedef _Float16 half8 __attribute__((ext_vector_type(8)));
typedef float f32x4 __attribute__((ext_vector_type(4)));

#define BATCH 8
#define CH 128
#define NPIX 2304   // 48*48
#define LOG2E 1.44269504088896f

__device__ __forceinline__ f32x4 mfma16(half8 a, half8 b, f32x4 c) {
    return __builtin_amdgcn_mfma_f32_16x16x32_f16(a, b, c, 0, 0, 0);
}

// ---------------- prep kernels ----------------

__global__ void k_convert_w(const float* __restrict__ Wq, const float* __restrict__ Wk,
                            const float* __restrict__ Wv, _Float16* __restrict__ Wh) {
    int i = blockIdx.x * 256 + threadIdx.x;          // 0..49151
    const float* src = (i < 16384) ? Wq : ((i < 32768) ? Wk : Wv);
    Wh[i] = (_Float16)src[i & 16383];
}

__global__ void k_pool(const float* __restrict__ x, float* __restrict__ y0) {
    int row = blockIdx.x;                             // b*128 + c
    const float* p = x + (size_t)row * NPIX;
    float s = 0.f;
    for (int t = threadIdx.x; t < NPIX; t += 256) s += p[t];
    for (int m = 1; m < 64; m <<= 1) s += __shfl_xor(s, m);
    __shared__ float ls[4];
    if ((threadIdx.x & 63) == 0) ls[threadIdx.x >> 6] = s;
    __syncthreads();
    if (threadIdx.x == 0) y0[row] = (ls[0] + ls[1] + ls[2] + ls[3]) * (1.0f / (float)NPIX);
}

__global__ void k_se(const float* __restrict__ y0, const float* __restrict__ w1,
                     const float* __restrict__ w2, float* __restrict__ scale) {
    int b = blockIdx.x, t = threadIdx.x;              // 128 threads
    __shared__ float ly[128];
    __shared__ float ly1[8];
    ly[t] = y0[b * 128 + t];
    __syncthreads();
    if (t < 8) {
        float a = 0.f;
        for (int c = 0; c < 128; ++c) a += w1[t * 128 + c] * ly[c];
        ly1[t] = fmaxf(a, 0.f);
    }
    __syncthreads();
    float a = 0.f;
    for (int r = 0; r < 8; ++r) a += w2[t * 8 + r] * ly1[r];
    scale[b * 128 + t] = 1.f / (1.f + __expf(-a));
}

// ---------------- QKV projection ----------------
// grid (18, 8, 3); block 256. which: 0=q (B,N,C), 1=k (B,N,C), 2=v (B,C,N)
__global__ __launch_bounds__(256) void k_proj(
        const float* __restrict__ x, const _Float16* __restrict__ Wh,
        const float* __restrict__ bq, const float* __restrict__ bk, const float* __restrict__ bv,
        _Float16* __restrict__ qT, _Float16* __restrict__ kT, _Float16* __restrict__ vN) {
    const int n0 = blockIdx.x * 128;
    const int b = blockIdx.y;
    const int which = blockIdx.z;
    const float* bias = (which == 0) ? bq : ((which == 1) ? bk : bv);
    const _Float16* W = Wh + which * 16384;

    __shared__ __align__(16) _Float16 xt[128 * 136];  // [n][c] pad+8

    const float* xb = x + (size_t)b * CH * NPIX + n0;
    const int t = threadIdx.x;
    for (int rep = 0; rep < 16; ++rep) {
        int flat = rep * 256 + t;       // 0..4095
        int c = flat >> 5;              // 0..127
        int n4 = (flat & 31) * 4;       // 0..124
        float4 v4 = *(const float4*)(xb + (size_t)c * NPIX + n4);
        xt[(n4 + 0) * 136 + c] = (_Float16)v4.x;
        xt[(n4 + 1) * 136 + c] = (_Float16)v4.y;
        xt[(n4 + 2) * 136 + c] = (_Float16)v4.z;
        xt[(n4 + 3) * 136 + c] = (_Float16)v4.w;
    }
    __syncthreads();

    const int lane = t & 63, w = t >> 6;
    const int ln15 = lane & 15, quad = lane >> 4;

    f32x4 zero4 = {0.f, 0.f, 0.f, 0.f};
    f32x4 acc[8][2];
    for (int mt = 0; mt < 8; ++mt) { acc[mt][0] = zero4; acc[mt][1] = zero4; }

    for (int ks = 0; ks < 4; ++ks) {
        half8 bf[2];
        for (int nt = 0; nt < 2; ++nt) {
            int n = w * 32 + nt * 16 + ln15;
            bf[nt] = *(const half8*)(xt + n * 136 + ks * 32 + quad * 8);
        }
        for (int mt = 0; mt < 8; ++mt) {
            half8 af = *(const half8*)(W + (mt * 16 + ln15) * 128 + ks * 32 + quad * 8);
            acc[mt][0] = mfma16(af, bf[0], acc[mt][0]);
            acc[mt][1] = mfma16(af, bf[1], acc[mt][1]);
        }
    }

    if (which == 2) {
        _Float16* vb = vN + (size_t)b * CH * NPIX;
        for (int mt = 0; mt < 8; ++mt)
            for (int nt = 0; nt < 2; ++nt)
                for (int r = 0; r < 4; ++r) {
                    int c = mt * 16 + quad * 4 + r;
                    int n = n0 + w * 32 + nt * 16 + ln15;
                    vb[(size_t)c * NPIX + n] = (_Float16)(acc[mt][nt][r] + bias[c]);
                }
    } else {
        __syncthreads();   // reuse xt as transpose buffer
        for (int mt = 0; mt < 8; ++mt)
            for (int nt = 0; nt < 2; ++nt)
                for (int r = 0; r < 4; ++r) {
                    int c = mt * 16 + quad * 4 + r;
                    int nl = w * 32 + nt * 16 + ln15;
                    xt[nl * 136 + c] = (_Float16)(acc[mt][nt][r] + bias[c]);
                }
        __syncthreads();
        _Float16* dst = ((which == 0) ? qT : kT) + ((size_t)b * NPIX + n0) * CH;
        for (int rep = 0; rep < 8; ++rep) {
            int nl = rep * 16 + (t >> 4);
            int c8 = (t & 15) * 8;
            *(half8*)(dst + nl * 128 + c8) = *(const half8*)(xt + nl * 136 + c8);
        }
    }
}

// ---------------- flash attention + fused epilogue ----------------
// grid (36, 8); block 256 (4 waves). Each block: 64 query rows, loops all j.
__global__ __launch_bounds__(256) void k_attn(
        const _Float16* __restrict__ qT, const _Float16* __restrict__ kT,
        const _Float16* __restrict__ vN, const float* __restrict__ x,
        const float* __restrict__ scale, const float* __restrict__ gamma_p,
        float* __restrict__ out) {
    const int i0 = blockIdx.x * 64;
    const int b = blockIdx.y;

    __shared__ __align__(16) _Float16 q_s[64 * 136];   // [i][c]
    __shared__ __align__(16) _Float16 k_s[64 * 136];   // [j][c]
    __shared__ __align__(16) _Float16 v_s[128 * 72];   // [c][j]
    __shared__ __align__(16) _Float16 p_s[64 * 72];    // [i][j]
    __shared__ float alpha_s[64];
    __shared__ float l_s[64];

    const int t = threadIdx.x;
    const int lane = t & 63, w = t >> 6;
    const int ln15 = lane & 15, quad = lane >> 4;

    { // stage Q once
        const _Float16* qb = qT + ((size_t)b * NPIX + i0) * CH;
        for (int rep = 0; rep < 4; ++rep) {
            int i = rep * 16 + (t >> 4), c8 = (t & 15) * 8;
            *(half8*)(q_s + i * 136 + c8) = *(const half8*)(qb + i * 128 + c8);
        }
    }
    __syncthreads();
    half8 qf[4];   // this wave's A-frags for rows 16w..16w+15, hoisted
    for (int kc = 0; kc < 4; ++kc)
        qf[kc] = *(const half8*)(q_s + (w * 16 + ln15) * 136 + kc * 32 + quad * 8);

    f32x4 zero4 = {0.f, 0.f, 0.f, 0.f};
    f32x4 os[2][4];   // O^T acc: c = 32w + ct*16 + quad*4+r, i col = it*16 + ln15
    for (int ct = 0; ct < 2; ++ct)
        for (int it = 0; it < 4; ++it) os[ct][it] = zero4;
    float mrow[4], lrow[4];
    for (int r = 0; r < 4; ++r) { mrow[r] = -1e30f; lrow[r] = 0.f; }

    for (int j0 = 0; j0 < NPIX; j0 += 64) {
        __syncthreads();   // previous iteration's LDS consumers done
        { // stage K tile [j][c]
            const _Float16* kb = kT + ((size_t)b * NPIX + j0) * CH;
            for (int rep = 0; rep < 4; ++rep) {
                int j = rep * 16 + (t >> 4), c8 = (t & 15) * 8;
                *(half8*)(k_s + j * 136 + c8) = *(const half8*)(kb + j * 128 + c8);
            }
        }
        { // stage V tile [c][j]
            const _Float16* vb = vN + (size_t)b * CH * NPIX + j0;
            for (int rep = 0; rep < 4; ++rep) {
                int c = rep * 32 + (t >> 3), j8 = (t & 7) * 8;
                *(half8*)(v_s + c * 72 + j8) = *(const half8*)(vb + (size_t)c * NPIX + j8);
            }
        }
        __syncthreads();

        // S strip (16 rows) = Q^T K
        f32x4 s[4];
        for (int jt = 0; jt < 4; ++jt) s[jt] = zero4;
        for (int kc = 0; kc < 4; ++kc)
            for (int jt = 0; jt < 4; ++jt) {
                half8 kf = *(const half8*)(k_s + (jt * 16 + ln15) * 136 + kc * 32 + quad * 8);
                s[jt] = mfma16(qf[kc], kf, s[jt]);
            }

        // online softmax on own 16 rows (row = 16w + quad*4 + r)
        float alpha[4];
        for (int r = 0; r < 4; ++r) {
            float mx = fmaxf(fmaxf(s[0][r], s[1][r]), fmaxf(s[2][r], s[3][r]));
            mx = fmaxf(mx, __shfl_xor(mx, 1));
            mx = fmaxf(mx, __shfl_xor(mx, 2));
            mx = fmaxf(mx, __shfl_xor(mx, 4));
            mx = fmaxf(mx, __shfl_xor(mx, 8));
            float mnew = fmaxf(mrow[r], mx);
            alpha[r] = exp2f((mrow[r] - mnew) * LOG2E);
            mrow[r] = mnew;
            float sum = 0.f;
            int rowoff = (w * 16 + quad * 4 + r) * 72;
            for (int jt = 0; jt < 4; ++jt) {
                float p = exp2f((s[jt][r] - mnew) * LOG2E);
                sum += p;
                p_s[rowoff + jt * 16 + ln15] = (_Float16)p;
            }
            sum += __shfl_xor(sum, 1);
            sum += __shfl_xor(sum, 2);
            sum += __shfl_xor(sum, 4);
            sum += __shfl_xor(sum, 8);
            lrow[r] = lrow[r] * alpha[r] + sum;
        }
        if (ln15 == 0)
            for (int r = 0; r < 4; ++r) alpha_s[w * 16 + quad * 4 + r] = alpha[r];
        __syncthreads();

        // O^T update: rescale by alpha (per i column), then O^T += V * P^T
        float av[4];
        for (int it = 0; it < 4; ++it) av[it] = alpha_s[it * 16 + ln15];
        for (int ct = 0; ct < 2; ++ct)
            for (int it = 0; it < 4; ++it) {
                os[ct][it][0] *= av[it]; os[ct][it][1] *= av[it];
                os[ct][it][2] *= av[it]; os[ct][it][3] *= av[it];
            }
        for (int ks = 0; ks < 2; ++ks) {
            half8 vf0 = *(const half8*)(v_s + (w * 32 + ln15) * 72 + ks * 32 + quad * 8);
            half8 vf1 = *(const half8*)(v_s + (w * 32 + 16 + ln15) * 72 + ks * 32 + quad * 8);
            for (int it = 0; it < 4; ++it) {
                half8 pf = *(const half8*)(p_s + (it * 16 + ln15) * 72 + ks * 32 + quad * 8);
                os[0][it] = mfma16(vf0, pf, os[0][it]);
                os[1][it] = mfma16(vf1, pf, os[1][it]);
            }
        }
    }

    if (ln15 == 0)
        for (int r = 0; r < 4; ++r) l_s[w * 16 + quad * 4 + r] = lrow[r];
    __syncthreads();

    const float gamma = gamma_p[0];
    const float* xb = x + (size_t)b * CH * NPIX;
    float* ob = out + (size_t)b * CH * NPIX;
    for (int ct = 0; ct < 2; ++ct)
        for (int r = 0; r < 4; ++r) {
            int c = w * 32 + ct * 16 + quad * 4 + r;
            float sc = scale[b * 128 + c];
            for (int it = 0; it < 4; ++it) {
                int i = i0 + it * 16 + ln15;
                float li = l_s[it * 16 + ln15];
                ob[(size_t)c * NPIX + i] =
                    gamma * (os[ct][it][r] / li) + xb[(size_t)c * NPIX + i] * sc;
            }
        }
}

// ---------------- host launcher ----------------
extern "C" void kernel_launch(void* const* d_in, const int* in_sizes, int n_in,
                              void* d_out, int out_size, void* d_ws, size_t ws_size,
                              hipStream_t stream) {
    const float* x     = (const float*)d_in[0];
    const float* Wq    = (const float*)d_in[1];
    const float* bq    = (const float*)d_in[2];
    const float* Wk    = (const float*)d_in[3];
    const float* bk    = (const float*)d_in[4];
    const float* Wv    = (const float*)d_in[5];
    const float* bv    = (const float*)d_in[6];
    const float* se_w1 = (const float*)d_in[7];
    const float* se_w2 = (const float*)d_in[8];
    const float* gamma = (const float*)d_in[9];
    float* out = (float*)d_out;

    char* ws = (char*)d_ws;
    const size_t qkv_elems = (size_t)BATCH * NPIX * CH;      // 2,359,296
    _Float16* qT = (_Float16*)(ws);
    _Float16* kT = (_Float16*)(ws + qkv_elems * 2);
    _Float16* vN = (_Float16*)(ws + qkv_elems * 4);
    _Float16* Wh = (_Float16*)(ws + qkv_elems * 6);          // 3*16384 f16
    float* y0    = (float*)   (ws + qkv_elems * 6 + 98304);
    float* scale = (float*)   (ws + qkv_elems * 6 + 98304 + 4096);

    k_convert_w<<<192, 256, 0, stream>>>(Wq, Wk, Wv, Wh);
    k_pool<<<BATCH * CH, 256, 0, stream>>>(x, y0);
    k_se<<<BATCH, 128, 0, stream>>>(y0, se_w1, se_w2, scale);
    k_proj<<<dim3(NPIX / 128, BATCH, 3), 256, 0, stream>>>(x, Wh, bq, bk, bv, qT, kT, vN);
    k_attn<<<dim3(NPIX / 64, BATCH), 256, 0, stream>>>(qT, kT, vN, x, scale, gamma, out);
}

// Round 2
// 197.182 us; speedup vs baseline: 1.0905x; 1.0905x over previous
//
#include <hip/hip_runtime.h>

typedef _Float16 half8 __attribute__((ext_vector_type(8)));
typedef _Float16 half4 __attribute__((ext_vector_type(4)));
typedef float f32x4 __attribute__((ext_vector_type(4)));

#define BATCH 8
#define CH 128
#define NPIX 2304   // 48*48
#define SPLIT 4
#define JPER (NPIX / SPLIT)          // 576 = 9 tiles of 64
#define BN (BATCH * NPIX)            // 18432
#define LOG2E 1.44269504088896f

__device__ __forceinline__ f32x4 mfma16(half8 a, half8 b, f32x4 c) {
    return __builtin_amdgcn_mfma_f32_16x16x32_f16(a, b, c, 0, 0, 0);
}

// ---------------- prep kernels ----------------

__global__ void k_convert_w(const float* __restrict__ Wq, const float* __restrict__ Wk,
                            const float* __restrict__ Wv, _Float16* __restrict__ Wh) {
    int i = blockIdx.x * 256 + threadIdx.x;          // 0..49151
    const float* src = (i < 16384) ? Wq : ((i < 32768) ? Wk : Wv);
    Wh[i] = (_Float16)src[i & 16383];
}

__global__ void k_pool(const float* __restrict__ x, float* __restrict__ y0) {
    int row = blockIdx.x;                             // b*128 + c
    const float4* p = (const float4*)(x + (size_t)row * NPIX);
    float s = 0.f;
    for (int t = threadIdx.x; t < NPIX / 4; t += 256) {
        float4 v = p[t];
        s += v.x + v.y + v.z + v.w;
    }
    for (int m = 1; m < 64; m <<= 1) s += __shfl_xor(s, m);
    __shared__ float ls[4];
    if ((threadIdx.x & 63) == 0) ls[threadIdx.x >> 6] = s;
    __syncthreads();
    if (threadIdx.x == 0) y0[row] = (ls[0] + ls[1] + ls[2] + ls[3]) * (1.0f / (float)NPIX);
}

__global__ void k_se(const float* __restrict__ y0, const float* __restrict__ w1,
                     const float* __restrict__ w2, float* __restrict__ scale) {
    int b = blockIdx.x, t = threadIdx.x;              // 128 threads
    __shared__ float ly[128];
    __shared__ float ly1[8];
    ly[t] = y0[b * 128 + t];
    __syncthreads();
    if (t < 8) {
        float a = 0.f;
        for (int c = 0; c < 128; ++c) a += w1[t * 128 + c] * ly[c];
        ly1[t] = fmaxf(a, 0.f);
    }
    __syncthreads();
    float a = 0.f;
    for (int r = 0; r < 8; ++r) a += w2[t * 8 + r] * ly1[r];
    scale[b * 128 + t] = 1.f / (1.f + __expf(-a));
}

// ---------------- x transpose: x[b][c][n] f32 -> xh[b][n][c] f16 ----------------
// grid (36, 8); block 256
__global__ __launch_bounds__(256) void k_xpose(const float* __restrict__ x,
                                               _Float16* __restrict__ xh) {
    const int n0 = blockIdx.x * 64, b = blockIdx.y;
    __shared__ __align__(16) _Float16 xt[64 * 136];
    const int t = threadIdx.x;
    const float* xb = x + (size_t)b * CH * NPIX + n0;
    const int n = t & 63;
    const int c0b = (t >> 6) * 4;
    for (int rep = 0; rep < 8; ++rep) {
        int c0 = c0b + rep * 16;
        half4 h;
        h[0] = (_Float16)xb[(size_t)(c0 + 0) * NPIX + n];
        h[1] = (_Float16)xb[(size_t)(c0 + 1) * NPIX + n];
        h[2] = (_Float16)xb[(size_t)(c0 + 2) * NPIX + n];
        h[3] = (_Float16)xb[(size_t)(c0 + 3) * NPIX + n];
        *(half4*)(xt + n * 136 + c0) = h;
    }
    __syncthreads();
    _Float16* dst = xh + ((size_t)b * NPIX + n0) * CH;
    for (int rep = 0; rep < 4; ++rep) {
        int nn = rep * 16 + (t >> 4), c8 = (t & 15) * 8;
        *(half8*)(dst + nn * 128 + c8) = *(const half8*)(xt + nn * 136 + c8);
    }
}

// ---------------- QKV projection ----------------
// grid (18, 8, 3); block 256. which: 0=q (B,N,C), 1=k (B,N,C), 2=v (B,C,N)
__global__ __launch_bounds__(256) void k_proj(
        const _Float16* __restrict__ xh, const _Float16* __restrict__ Wh,
        const float* __restrict__ bq, const float* __restrict__ bk, const float* __restrict__ bv,
        _Float16* __restrict__ qT, _Float16* __restrict__ kT, _Float16* __restrict__ vN) {
    const int n0 = blockIdx.x * 128;
    const int b = blockIdx.y;
    const int which = blockIdx.z;
    const float* bias = (which == 0) ? bq : ((which == 1) ? bk : bv);
    const _Float16* W = Wh + which * 16384;

    __shared__ __align__(16) _Float16 xt[128 * 128];  // swizzled tile

    const int t = threadIdx.x;
    { // stage xh tile [n][c], swizzled
        const _Float16* src = xh + ((size_t)b * NPIX + n0) * CH;
        for (int rep = 0; rep < 8; ++rep) {
            int row = rep * 16 + (t >> 4), ch = t & 15;
            *(half8*)(xt + row * 128 + ((ch ^ (row & 7)) * 8)) =
                *(const half8*)(src + row * 128 + ch * 8);
        }
    }
    __syncthreads();

    const int lane = t & 63, w = t >> 6;
    const int ln15 = lane & 15, quad = lane >> 4;

    f32x4 zero4 = {0.f, 0.f, 0.f, 0.f};
    f32x4 acc[8][2];
    for (int mt = 0; mt < 8; ++mt) { acc[mt][0] = zero4; acc[mt][1] = zero4; }

    for (int ks = 0; ks < 4; ++ks) {
        half8 bf[2];
        for (int nt = 0; nt < 2; ++nt) {
            int row = w * 32 + nt * 16 + ln15;
            int ch = ks * 4 + quad;
            bf[nt] = *(const half8*)(xt + row * 128 + ((ch ^ (row & 7)) * 8));
        }
        for (int mt = 0; mt < 8; ++mt) {
            half8 af = *(const half8*)(W + (mt * 16 + ln15) * 128 + ks * 32 + quad * 8);
            acc[mt][0] = mfma16(af, bf[0], acc[mt][0]);
            acc[mt][1] = mfma16(af, bf[1], acc[mt][1]);
        }
    }
    __syncthreads();   // xt reuse as transpose buffer

    if (which == 2) {
        // [c][n] swizzled, then coalesced store to vN (B,C,N)
        for (int mt = 0; mt < 8; ++mt)
            for (int nt = 0; nt < 2; ++nt)
                for (int r = 0; r < 4; ++r) {
                    int c = mt * 16 + quad * 4 + r;
                    int nl = w * 32 + nt * 16 + ln15;
                    xt[c * 128 + (((nl >> 3) ^ (c & 7)) * 8) + (nl & 7)] =
                        (_Float16)(acc[mt][nt][r] + bias[c]);
                }
        __syncthreads();
        _Float16* vb = vN + (size_t)b * CH * NPIX + n0;
        for (int rep = 0; rep < 8; ++rep) {
            int c = rep * 16 + (t >> 4), ch = t & 15;
            *(half8*)(vb + (size_t)c * NPIX + ch * 8) =
                *(const half8*)(xt + c * 128 + ((ch ^ (c & 7)) * 8));
        }
    } else {
        // [n][c] swizzled, then coalesced store to qT/kT (B,N,C)
        for (int mt = 0; mt < 8; ++mt)
            for (int nt = 0; nt < 2; ++nt)
                for (int r = 0; r < 4; ++r) {
                    int c = mt * 16 + quad * 4 + r;
                    int nl = w * 32 + nt * 16 + ln15;
                    xt[nl * 128 + (((c >> 3) ^ (nl & 7)) * 8) + (c & 7)] =
                        (_Float16)(acc[mt][nt][r] + bias[c]);
                }
        __syncthreads();
        _Float16* dst = ((which == 0) ? qT : kT) + ((size_t)b * NPIX + n0) * CH;
        for (int rep = 0; rep < 8; ++rep) {
            int nl = rep * 16 + (t >> 4), ch = t & 15;
            *(half8*)(dst + nl * 128 + ch * 8) =
                *(const half8*)(xt + nl * 128 + ((ch ^ (nl & 7)) * 8));
        }
    }
}

// ---------------- flash attention, KV-split partials ----------------
// grid (36, 8, SPLIT); block 256 (4 waves). 64 q-rows per block, JPER kv cols.
__global__ __launch_bounds__(256) void k_attn(
        const _Float16* __restrict__ qT, const _Float16* __restrict__ kT,
        const _Float16* __restrict__ vN,
        _Float16* __restrict__ o_part, float* __restrict__ g_m, float* __restrict__ g_l) {
    const int i0 = blockIdx.x * 64;
    const int b = blockIdx.y;
    const int split = blockIdx.z;

    __shared__ __align__(16) _Float16 k_s[64 * 128];   // [j][c] swizzled; Q staged here first
    __shared__ __align__(16) _Float16 v_s[128 * 64];   // [c][j] swizzled; O^T buffer at end
    __shared__ __align__(16) _Float16 p_s[64 * 64];    // [i][j] swizzled
    __shared__ float alpha_s[64];

    const int t = threadIdx.x;
    const int lane = t & 63, w = t >> 6;
    const int ln15 = lane & 15, quad = lane >> 4;

    { // stage Q once (into k_s region), hoist frags to regs
        const _Float16* qb = qT + ((size_t)b * NPIX + i0) * CH;
        for (int rep = 0; rep < 4; ++rep) {
            int row = rep * 16 + (t >> 4), ch = t & 15;
            *(half8*)(k_s + row * 128 + ((ch ^ (row & 7)) * 8)) =
                *(const half8*)(qb + row * 128 + ch * 8);
        }
    }
    __syncthreads();
    half8 qf[4];
    for (int kc = 0; kc < 4; ++kc) {
        int row = w * 16 + ln15, ch = kc * 4 + quad;
        qf[kc] = *(const half8*)(k_s + row * 128 + ((ch ^ (row & 7)) * 8));
    }

    f32x4 zero4 = {0.f, 0.f, 0.f, 0.f};
    f32x4 os[2][4];
    for (int ct = 0; ct < 2; ++ct)
        for (int it = 0; it < 4; ++it) os[ct][it] = zero4;
    float mrow[4], lrow[4];
    for (int r = 0; r < 4; ++r) { mrow[r] = -1e30f; lrow[r] = 0.f; }

    for (int j0 = split * JPER; j0 < (split + 1) * JPER; j0 += 64) {
        __syncthreads();   // prior consumers of k_s/v_s done (also guards Q hoist)
        { // stage K tile [j][c] swizzled
            const _Float16* kb = kT + ((size_t)b * NPIX + j0) * CH;
            for (int rep = 0; rep < 4; ++rep) {
                int row = rep * 16 + (t >> 4), ch = t & 15;
                *(half8*)(k_s + row * 128 + ((ch ^ (row & 7)) * 8)) =
                    *(const half8*)(kb + row * 128 + ch * 8);
            }
        }
        { // stage V tile [c][j] swizzled
            const _Float16* vb = vN + (size_t)b * CH * NPIX + j0;
            for (int rep = 0; rep < 4; ++rep) {
                int c = rep * 32 + (t >> 3), ch = t & 7;
                *(half8*)(v_s + c * 64 + ((ch ^ (c & 7)) * 8)) =
                    *(const half8*)(vb + (size_t)c * NPIX + ch * 8);
            }
        }
        __syncthreads();

        // S strip (16 rows of this wave) = Q^T K
        f32x4 s[4];
        for (int jt = 0; jt < 4; ++jt) s[jt] = zero4;
        for (int kc = 0; kc < 4; ++kc)
            for (int jt = 0; jt < 4; ++jt) {
                int row = jt * 16 + ln15, ch = kc * 4 + quad;
                half8 kf = *(const half8*)(k_s + row * 128 + ((ch ^ (row & 7)) * 8));
                s[jt] = mfma16(qf[kc], kf, s[jt]);
            }

        // online softmax on own rows (row = 16w + quad*4 + r)
        float alpha[4];
        for (int r = 0; r < 4; ++r) {
            float mx = fmaxf(fmaxf(s[0][r], s[1][r]), fmaxf(s[2][r], s[3][r]));
            mx = fmaxf(mx, __shfl_xor(mx, 1));
            mx = fmaxf(mx, __shfl_xor(mx, 2));
            mx = fmaxf(mx, __shfl_xor(mx, 4));
            mx = fmaxf(mx, __shfl_xor(mx, 8));
            float mnew = fmaxf(mrow[r], mx);
            alpha[r] = exp2f((mrow[r] - mnew) * LOG2E);
            mrow[r] = mnew;
            float sum = 0.f;
            int prow = w * 16 + quad * 4 + r;
            for (int jt = 0; jt < 4; ++jt) {
                float p = exp2f((s[jt][r] - mnew) * LOG2E);
                sum += p;
                p_s[prow * 64 + (((jt * 2 + (ln15 >> 3)) ^ (prow & 7)) * 8) + (ln15 & 7)] =
                    (_Float16)p;
            }
            sum += __shfl_xor(sum, 1);
            sum += __shfl_xor(sum, 2);
            sum += __shfl_xor(sum, 4);
            sum += __shfl_xor(sum, 8);
            lrow[r] = lrow[r] * alpha[r] + sum;
        }
        if (ln15 == 0)
            for (int r = 0; r < 4; ++r) alpha_s[w * 16 + quad * 4 + r] = alpha[r];
        __syncthreads();

        // O^T rescale + O^T += V * P^T
        float av[4];
        for (int it = 0; it < 4; ++it) av[it] = alpha_s[it * 16 + ln15];
        for (int ct = 0; ct < 2; ++ct)
            for (int it = 0; it < 4; ++it) {
                os[ct][it][0] *= av[it]; os[ct][it][1] *= av[it];
                os[ct][it][2] *= av[it]; os[ct][it][3] *= av[it];
            }
        for (int ks = 0; ks < 2; ++ks) {
            int ch = ks * 4 + quad;
            int c0 = w * 32 + ln15, c1 = w * 32 + 16 + ln15;
            half8 vf0 = *(const half8*)(v_s + c0 * 64 + ((ch ^ (c0 & 7)) * 8));
            half8 vf1 = *(const half8*)(v_s + c1 * 64 + ((ch ^ (c1 & 7)) * 8));
            for (int it = 0; it < 4; ++it) {
                int prow = it * 16 + ln15;
                half8 pf = *(const half8*)(p_s + prow * 64 + ((ch ^ (prow & 7)) * 8));
                os[0][it] = mfma16(vf0, pf, os[0][it]);
                os[1][it] = mfma16(vf1, pf, os[1][it]);
            }
        }
    }

    // epilogue: write raw partial O (f16) via LDS transpose, and m/l (f32)
    __syncthreads();   // all PV reads of v_s/p_s done
    if (ln15 == 0)
        for (int r = 0; r < 4; ++r) {
            int i = i0 + w * 16 + quad * 4 + r;
            g_m[(size_t)(split * BATCH + b) * NPIX + i] = mrow[r];
            g_l[(size_t)(split * BATCH + b) * NPIX + i] = lrow[r];
        }
    for (int ct = 0; ct < 2; ++ct)
        for (int it = 0; it < 4; ++it)
            for (int r = 0; r < 4; ++r) {
                int c = w * 32 + ct * 16 + quad * 4 + r;
                int chk = it * 2 + (ln15 >> 3);
                v_s[c * 64 + ((chk ^ (c & 7)) * 8) + (ln15 & 7)] =
                    (_Float16)os[ct][it][r];
            }
    __syncthreads();
    _Float16* op = o_part + (size_t)(split * BATCH + b) * CH * NPIX;
    for (int rep = 0; rep < 4; ++rep) {
        int c = rep * 32 + (t >> 3), ch = t & 7;
        *(half8*)(op + (size_t)c * NPIX + i0 + ch * 8) =
            *(const half8*)(v_s + c * 64 + ((ch ^ (c & 7)) * 8));
    }
}

// ---------------- combine weights: per (b,i) ----------------
__global__ void k_cw(const float* __restrict__ g_m, const float* __restrict__ g_l,
                     float* __restrict__ wgt) {
    int idx = blockIdx.x * 256 + threadIdx.x;   // 0..BN-1
    float m[SPLIT], l[SPLIT];
    float M = -1e30f;
    for (int s = 0; s < SPLIT; ++s) {
        m[s] = g_m[s * BN + idx];
        l[s] = g_l[s * BN + idx];
        M = fmaxf(M, m[s]);
    }
    float L = 0.f, e[SPLIT];
    for (int s = 0; s < SPLIT; ++s) {
        e[s] = exp2f((m[s] - M) * LOG2E);
        L += e[s] * l[s];
    }
    float inv = 1.f / L;
    for (int s = 0; s < SPLIT; ++s) wgt[s * BN + idx] = e[s] * inv;
}

// ---------------- combine + fused SE epilogue ----------------
// grid 1152; block 256; 8 elems/thread
__global__ __launch_bounds__(256) void k_combine(
        const _Float16* __restrict__ o_part, const float* __restrict__ wgt,
        const float* __restrict__ x, const float* __restrict__ scale,
        const float* __restrict__ gamma_p, float* __restrict__ out) {
    int tid = blockIdx.x * 256 + threadIdx.x;    // 0..294911
    int i8 = (tid % (NPIX / 8)) * 8;
    int bc = tid / (NPIX / 8);                   // b*128 + c
    int b = bc >> 7;
    size_t base = (size_t)bc * NPIX + i8;
    int widx = b * NPIX + i8;

    float acc[8] = {0.f, 0.f, 0.f, 0.f, 0.f, 0.f, 0.f, 0.f};
    for (int s = 0; s < SPLIT; ++s) {
        half8 o = *(const half8*)(o_part + (size_t)s * BATCH * CH * NPIX + base);
        float4 w0 = *(const float4*)(wgt + s * BN + widx);
        float4 w1 = *(const float4*)(wgt + s * BN + widx + 4);
        acc[0] += w0.x * (float)o[0]; acc[1] += w0.y * (float)o[1];
        acc[2] += w0.z * (float)o[2]; acc[3] += w0.w * (float)o[3];
        acc[4] += w1.x * (float)o[4]; acc[5] += w1.y * (float)o[5];
        acc[6] += w1.z * (float)o[6]; acc[7] += w1.w * (float)o[7];
    }
    float sc = scale[bc];
    float g = gamma_p[0];
    float4 x0 = *(const float4*)(x + base);
    float4 x1 = *(const float4*)(x + base + 4);
    float4 r0, r1;
    r0.x = g * acc[0] + x0.x * sc; r0.y = g * acc[1] + x0.y * sc;
    r0.z = g * acc[2] + x0.z * sc; r0.w = g * acc[3] + x0.w * sc;
    r1.x = g * acc[4] + x1.x * sc; r1.y = g * acc[5] + x1.y * sc;
    r1.z = g * acc[6] + x1.z * sc; r1.w = g * acc[7] + x1.w * sc;
    *(float4*)(out + base) = r0;
    *(float4*)(out + base + 4) = r1;
}

// ---------------- host launcher ----------------
extern "C" void kernel_launch(void* const* d_in, const int* in_sizes, int n_in,
                              void* d_out, int out_size, void* d_ws, size_t ws_size,
                              hipStream_t stream) {
    const float* x     = (const float*)d_in[0];
    const float* Wq    = (const float*)d_in[1];
    const float* bq    = (const float*)d_in[2];
    const float* Wk    = (const float*)d_in[3];
    const float* bk    = (const float*)d_in[4];
    const float* Wv    = (const float*)d_in[5];
    const float* bv    = (const float*)d_in[6];
    const float* se_w1 = (const float*)d_in[7];
    const float* se_w2 = (const float*)d_in[8];
    const float* gamma = (const float*)d_in[9];
    float* out = (float*)d_out;

    char* ws = (char*)d_ws;
    const size_t E = (size_t)BATCH * NPIX * CH;          // 2,359,296 elems
    _Float16* qT = (_Float16*)(ws);                      // E f16
    _Float16* kT = (_Float16*)(ws + E * 2);
    _Float16* vN = (_Float16*)(ws + E * 4);
    _Float16* xh = (_Float16*)(ws + E * 6);
    _Float16* op = (_Float16*)(ws + E * 8);              // SPLIT*E f16
    char* tail   = ws + E * 8 + (size_t)SPLIT * E * 2;
    _Float16* Wh = (_Float16*)(tail);                    // 49152 f16
    float* g_m   = (float*)(tail + 98304);               // SPLIT*BN f32
    float* g_l   = (float*)(tail + 98304 + SPLIT * BN * 4);
    float* wgt   = (float*)(tail + 98304 + 2 * SPLIT * BN * 4);
    float* y0    = (float*)(tail + 98304 + 3 * SPLIT * BN * 4);
    float* scale = (float*)(tail + 98304 + 3 * SPLIT * BN * 4 + 4096);

    k_convert_w<<<192, 256, 0, stream>>>(Wq, Wk, Wv, Wh);
    k_pool<<<BATCH * CH, 256, 0, stream>>>(x, y0);
    k_se<<<BATCH, 128, 0, stream>>>(y0, se_w1, se_w2, scale);
    k_xpose<<<dim3(NPIX / 64, BATCH), 256, 0, stream>>>(x, xh);
    k_proj<<<dim3(NPIX / 128, BATCH, 3), 256, 0, stream>>>(xh, Wh, bq, bk, bv, qT, kT, vN);
    k_attn<<<dim3(NPIX / 64, BATCH, SPLIT), 256, 0, stream>>>(qT, kT, vN, op, g_m, g_l);
    k_cw<<<BN / 256, 256, 0, stream>>>(g_m, g_l, wgt);
    k_combine<<<(int)(E / 8 / 256), 256, 0, stream>>>(op, wgt, x, scale, gamma, out);
}